// Round 14
// baseline (104.136 us; speedup 1.0000x reference)
//
#include <hip/hip_runtime.h>
#include <cstdint>

#define N_ATOMS 16384
#define NBLK 64
#define NTHR 256
#define G 24
#define NCELLS 13824
#define NCELLS_PAD 14336
#define CPT 14                    // cells per thread in K2 scan
#define BOX_LO -48.0f
#define INV_CELL 0.25f            // cell side 4.0
#define SINIT 3.0e38f

// ws layout:
#define OFF_COUNTS 0              // int[2]: n_ctx, n_gen
#define OFF_BLKGEN 256            // int[64]
#define OFF_BLKGOFF 512           // int[64]
#define OFF_FLAGS 1024            // u64[256] gen bit per atom
#define OFF_CNT 3072              // int[14336] cell counts -> cursors
#define OFF_START 60416           // int[14337] cell starts
#define OFF_GENIDX 118016         // int[16384]
#define OFF_CTX4 183552           // float4[16384] cell-sorted (x,y,z,|x|^2)

__device__ __forceinline__ int cell1(float x) {
    int c = (int)floorf((x - BOX_LO) * INV_CELL);
    return min(max(c, 0), G - 1);
}

__device__ __forceinline__ void ins3(float v, int vi,
                                     float& s1, float& s2, float& s3,
                                     int& i1, int& i2, int& i3)
{
    const bool b1 = v < s1, b2 = v < s2, b3 = v < s3;
    s3 = b2 ? s2 : (b3 ? v : s3);   i3 = b2 ? i2 : (b3 ? vi : i3);
    s2 = b1 ? s1 : (b2 ? v : s2);   i2 = b1 ? i1 : (b2 ? vi : i2);
    s1 = b1 ? v : s1;               i1 = b1 ? vi : i1;
}

__device__ __forceinline__ void ins3v(float v, float& s1, float& s2, float& s3)
{
    const bool b1 = v < s1, b2 = v < s2, b3 = v < s3;
    s3 = b2 ? s2 : (b3 ? v : s3);
    s2 = b1 ? s1 : (b2 ? v : s2);
    s1 = b1 ? v : s1;
}

__global__ __launch_bounds__(256)
void k0_zero(int4* __restrict__ cell_cnt4)
{
    cell_cnt4[blockIdx.x * 256 + threadIdx.x] = make_int4(0, 0, 0, 0);
}

__global__ __launch_bounds__(NTHR)
void k1_classify(const float* __restrict__ X,
                 const int* __restrict__ block_ids,
                 const unsigned int* __restrict__ mask,
                 const float* __restrict__ base_noise,
                 float* __restrict__ out,
                 unsigned long long* __restrict__ flags,
                 int* __restrict__ blk_gen,
                 int* __restrict__ cell_cnt)
{
    __shared__ int sflag;
    __shared__ int wg[4];
    const int t = threadIdx.x;
    const int wave = t >> 6, lane = t & 63;

    // mask dtype probe: int32 0/1 values vs packed bool bytes (R2-R13 validated)
    if (t == 0) sflag = 0;
    __syncthreads();
    if (mask[t] > 1u) sflag = 1;    // benign same-value race
    __syncthreads();
    const bool is_u8 = (sflag != 0);
    const unsigned char* m8 = (const unsigned char*)mask;

    const int i = blockIdx.x * NTHR + t;
    const int bid = block_ids[i];
    const bool g = is_u8 ? (m8[bid] != 0) : (mask[bid] != 0u);

    out[3 * i + 0] = base_noise[3 * i + 0];
    out[3 * i + 1] = base_noise[3 * i + 1];
    out[3 * i + 2] = base_noise[3 * i + 2];

    const unsigned long long mg = __ballot(g);
    if (lane == 0) { flags[blockIdx.x * 4 + wave] = mg; wg[wave] = __popcll(mg); }
    __syncthreads();
    if (t == 0) blk_gen[blockIdx.x] = wg[0] + wg[1] + wg[2] + wg[3];

    if (!g) {
        const float x = X[3 * i], y = X[3 * i + 1], z = X[3 * i + 2];
        const int cx = cell1(x), cy = cell1(y), cz = cell1(z);
        atomicAdd(&cell_cnt[(cz * G + cy) * G + cx], 1);
    }
}

__global__ __launch_bounds__(1024)
void k2_scan(int* __restrict__ cell_cnt,
             int* __restrict__ cell_start,
             const int* __restrict__ blk_gen,
             int* __restrict__ blk_goff,
             int* __restrict__ counts)
{
    const int t = threadIdx.x;
    const int wave = t >> 6, lane = t & 63;
    int loc[CPT]; int sum = 0;
    #pragma unroll
    for (int k = 0; k < CPT; ++k) {
        const int v = cell_cnt[t * CPT + k];
        loc[k] = sum; sum += v;
    }
    int v = sum;
    #pragma unroll
    for (int d = 1; d < 64; d <<= 1) { const int u = __shfl_up(v, d); if (lane >= d) v += u; }
    __shared__ int wsum[16], wexc[16];
    if (lane == 63) wsum[wave] = v;
    __syncthreads();
    if (t < 16) {
        int v2 = wsum[t];
        const int orig = v2;
        #pragma unroll
        for (int d = 1; d < 16; d <<= 1) { const int u = __shfl_up(v2, d); if (t >= d) v2 += u; }
        wexc[t] = v2 - orig;
    }
    __syncthreads();
    const int base = wexc[wave] + (v - sum);
    #pragma unroll
    for (int k = 0; k < CPT; ++k) {
        cell_start[t * CPT + k] = base + loc[k];
        cell_cnt[t * CPT + k] = 0;            // reset -> scatter cursors
    }
    if (t == 1023) cell_start[NCELLS_PAD] = base + sum;
    __syncthreads();
    if (t < 64) {
        const int o = blk_gen[t];
        int s = o;
        #pragma unroll
        for (int d = 1; d < 64; d <<= 1) { const int u = __shfl_up(s, d); if (t >= d) s += u; }
        blk_goff[t] = s - o;
        if (t == 63) { counts[1] = s; counts[0] = N_ATOMS - s; }
    }
}

__global__ __launch_bounds__(NTHR)
void k3_scatter(const float* __restrict__ X,
                const unsigned long long* __restrict__ flags,
                const int* __restrict__ blk_goff,
                const int* __restrict__ cell_start,
                int* __restrict__ cell_cur,
                float4* __restrict__ ctx4s,
                int* __restrict__ genidx)
{
    const int t = threadIdx.x;
    const int wave = t >> 6, lane = t & 63;
    const int i = blockIdx.x * NTHR + t;
    const unsigned long long fw = flags[blockIdx.x * 4 + wave];
    const bool g = (fw >> lane) & 1ull;
    int og = blk_goff[blockIdx.x];
    int oc = blockIdx.x * NTHR - og;
    #pragma unroll
    for (int w = 0; w < 4; ++w) {
        if (w < wave) {
            const int p = __popcll(flags[blockIdx.x * 4 + w]);
            og += p; oc += 64 - p;
        }
    }
    const unsigned long long below = (1ull << lane) - 1ull;
    og += __popcll(fw & below);
    oc += __popcll((~fw) & below);
    if (g) {
        genidx[og] = i;
    } else {
        const float x = X[3 * i], y = X[3 * i + 1], z = X[3 * i + 2];
        float xn = x * x; xn += y * y; xn += z * z;
        const int cx = cell1(x), cy = cell1(y), cz = cell1(z);
        const int c = (cz * G + cy) * G + cx;
        const int pos = cell_start[c] + atomicAdd(&cell_cur[c], 1);
        ctx4s[pos] = make_float4(x, y, z, xn);
    }
}

// One 64-lane wave per gen atom. DS-pipe-minimized (R13); IDEMPOTENT:
// pure gather from ws -> deterministic overwrite of out[gen atoms].
__global__ __launch_bounds__(512)
void k4_search(const float* __restrict__ X,
               const float* __restrict__ cnoise,
               const int* __restrict__ counts,
               const int* __restrict__ cell_start,
               const float4* __restrict__ ctx4s,
               const int* __restrict__ genidx,
               float* __restrict__ out)
{
    const int n_gen = counts[1];
    const int wave = threadIdx.x >> 6, lane = threadIdx.x & 63;
    const int slot = (int)blockIdx.x * 8 + wave;
    if (slot >= n_gen) return;

    const int ai = genidx[slot];
    const float qx = X[3 * ai], qy = X[3 * ai + 1], qz = X[3 * ai + 2];
    float xnq = qx * qx; xnq += qy * qy; xnq += qz * qz;
    const int cqx = cell1(qx), cqy = cell1(qy), cqz = cell1(qz);

    float s1 = SINIT, s2 = SINIT, s3 = SINIT;
    int i1 = 0, i2 = 0, i3 = 0;

    // ---- phase A: r<=1 box as 9 row-segments, shuffle-free scan ----
    {
        int st = 0, cnt = 0;
        if (lane < 9) {
            const int dy = lane % 3 - 1, dz = lane / 3 - 1;
            const int cy = cqy + dy, cz = cqz + dz;
            if ((unsigned)cy < G && (unsigned)cz < G) {
                const int xlo = max(cqx - 1, 0), xhi = min(cqx + 1, G - 1);
                const int c0 = (cz * G + cy) * G + xlo;
                st = cell_start[c0];
                cnt = cell_start[c0 + (xhi - xlo + 1)] - st;
            }
        }
        int stv[9], base[10];
        base[0] = 0;
        #pragma unroll
        for (int k = 0; k < 9; ++k) {
            stv[k] = __builtin_amdgcn_readlane(st, k);     // VALU, uniform
            base[k + 1] = base[k] + __builtin_amdgcn_readlane(cnt, k);
        }
        const int T = base[9];
        const int nro = (T + 63) >> 6;
        if (nro > 0) {
            auto calcP = [&](int j) -> int {
                const int jc = min(j, T - 1);
                int p = stv[0] + jc;
                #pragma unroll
                for (int k = 1; k < 9; ++k)
                    p = (jc >= base[k]) ? stv[k] + (jc - base[k]) : p;
                return p;
            };
            int p0 = calcP(lane);
            float4 cc0 = ctx4s[p0];
            for (int ro = 0; ro < nro; ++ro) {
                int p1 = p0; float4 cc1 = cc0;
                if (ro + 1 < nro) { p1 = calcP((ro + 1) * 64 + lane); cc1 = ctx4s[p1]; }
                if (ro * 64 + lane < T) {
                    const float dot = qx * cc0.x + qy * cc0.y + qz * cc0.z;
                    const float sq = (xnq + cc0.w) - 2.0f * dot;
                    ins3(sq, p0, s1, s2, s3, i1, i2, i3);
                }
                p0 = p1; cc0 = cc1;
            }
        }
    }

    // ballot-count convergence: >=3 values with v+0.01<bnd  <=>  m3+0.01<bnd
    auto converged = [&](float bnd) -> bool {
        const int c = __popcll(__ballot(s1 + 0.01f < bnd))
                    + __popcll(__ballot(s2 + 0.01f < bnd))
                    + __popcll(__ballot(s3 + 0.01f < bnd));
        return c >= 3;
    };

    bool done = converged(16.0f);            // bnd = (4*1)^2

    if (!done) {
        // ---- rare: ring levels (P,R] = (1,2], (2,4], (4,8] (R12 verbatim) ----
        auto searchOwner = [&](int ebase_r, int jc) -> int {
            int L = 0;
            #pragma unroll
            for (int stp = 32; stp >= 1; stp >>= 1) {
                const int cand = L + stp;
                const int bv = __shfl(ebase_r, cand);
                if (bv <= jc) L = cand;
            }
            return L;
        };
        auto flatScan = [&](int T, int ebase_r, int pk_r) {
            const int iters = (T + 63) >> 6;
            if (iters == 0) return;
            int jc0 = min(lane, T - 1);
            int p0 = __shfl(pk_r, searchOwner(ebase_r, jc0)) + jc0;
            float4 cc0 = ctx4s[p0];
            for (int it = 0; it < iters; ++it) {
                int p1 = p0; float4 cc1 = cc0;
                if (it + 1 < iters) {
                    const int jc1 = min((it + 1) * 64 + lane, T - 1);
                    p1 = __shfl(pk_r, searchOwner(ebase_r, jc1)) + jc1;
                    cc1 = ctx4s[p1];
                }
                if (it * 64 + lane < T) {
                    const float dot = qx * cc0.x + qy * cc0.y + qz * cc0.z;
                    const float sq = (xnq + cc0.w) - 2.0f * dot;
                    ins3(sq, p0, s1, s2, s3, i1, i2, i3);
                }
                p0 = p1; cc0 = cc1;
            }
        };
        auto prefixT = [&](int cnt, int& ebase_r, int& T) {
            int pre = cnt;
            #pragma unroll
            for (int d = 1; d < 64; d <<= 1) {
                const int u = __shfl_up(pre, d);
                if (lane >= d) pre += u;
            }
            T = __shfl(pre, 63);
            ebase_r = pre - cnt;
        };
        auto ringScan = [&](int P, int R) {
            const int B = 2 * R + 1;
            const int NR = B * B;
            const int NS = 2 * NR;
            auto segRange = [&](int u, int& st, int& cnt) {
                st = 0; cnt = 0;
                if (u >= NS) return;
                const int side = (u >= NR) ? 1 : 0;
                const int v = side ? u - NR : u;
                const int dy = v % B - R, dz = v / B - R;
                const int cy = cqy + dy, cz = cqz + dz;
                if ((unsigned)cy >= G || (unsigned)cz >= G) return;
                const bool inner = max(abs(dy), abs(dz)) <= P;
                int xlo, xhi;
                if (inner) {
                    if (side) { xlo = cqx + P + 1; xhi = cqx + R; }
                    else      { xlo = cqx - R;     xhi = cqx - P - 1; }
                } else {
                    if (side) return;
                    xlo = cqx - R; xhi = cqx + R;
                }
                xlo = max(xlo, 0); xhi = min(xhi, G - 1);
                if (xlo > xhi) return;
                const int c0 = (cz * G + cy) * G + xlo;
                st = cell_start[c0];
                cnt = cell_start[c0 + (xhi - xlo + 1)] - st;
            };
            const int nro = (NS + 63) >> 6;
            int st0, c0r;
            segRange(lane, st0, c0r);
            for (int ro = 0; ro < nro; ++ro) {
                int st1 = st0, c1r = c0r;
                if (ro + 1 < nro) segRange((ro + 1) * 64 + lane, st1, c1r);
                int eb, Tr;
                prefixT(c0r, eb, Tr);
                if (Tr > 0) flatScan(Tr, eb, st0 - eb);
                st0 = st1; c0r = c1r;
            }
        };

        #pragma unroll
        for (int li = 1; li < 4; ++li) {
            if (!done) {
                const int R = 1 << li;                 // 2,4,8
                ringScan(1 << (li - 1), R);
                done = converged((float)(4 * R) * (float)(4 * R));
            }
        }
        if (!done) {
            // exhaustive restart (exact, duplicate-free; ~never taken)
            s1 = SINIT; s2 = SINIT; s3 = SINIT;
            i1 = 0; i2 = 0; i3 = 0;
            const int n_ctx = counts[0];
            for (int base = 0; base < n_ctx; base += 64) {
                const int p = base + lane;
                if (p < n_ctx) {
                    const float4 cc = ctx4s[p];
                    const float dot = qx * cc.x + qy * cc.y + qz * cc.z;
                    const float sq = (xnq + cc.w) - 2.0f * dot;
                    ins3(sq, p, s1, s2, s3, i1, i2, i3);
                }
            }
        }
    }

    // final full merge with indices (each candidate lives in exactly one lane)
    #pragma unroll
    for (int m = 1; m < 64; m <<= 1) {
        const float a = __shfl_xor(s1, m); const int ja = __shfl_xor(i1, m);
        const float b = __shfl_xor(s2, m); const int jb = __shfl_xor(i2, m);
        const float c = __shfl_xor(s3, m); const int jc = __shfl_xor(i3, m);
        ins3(a, ja, s1, s2, s3, i1, i2, i3);
        ins3(b, jb, s1, s2, s3, i1, i2, i3);
        ins3(c, jc, s1, s2, s3, i1, i2, i3);
    }

    if (lane == 0) {
        const float d1 = sqrtf(fmaxf(s1, 0.0f) + 1e-12f);
        const float d2 = sqrtf(fmaxf(s2, 0.0f) + 1e-12f);
        const float d3 = sqrtf(fmaxf(s3, 0.0f) + 1e-12f);
        float w1 = 1.0f / (d1 + 1e-8f);
        float w2 = 1.0f / (d2 + 1e-8f);
        float w3 = 1.0f / (d3 + 1e-8f);
        float wsum = w1 + w2;
        wsum += w3;
        w1 /= wsum; w2 /= wsum; w3 /= wsum;
        const float4 c1 = ctx4s[i1];
        const float4 c2 = ctx4s[i2];
        const float4 c3 = ctx4s[i3];
        float cxo = w1 * c1.x + w2 * c2.x; cxo += w3 * c3.x;
        float cyo = w1 * c1.y + w2 * c2.y; cyo += w3 * c3.y;
        float czo = w1 * c1.z + w2 * c2.z; czo += w3 * c3.z;
        out[3 * ai + 0] = cxo + 0.5f * cnoise[3 * ai + 0];
        out[3 * ai + 1] = cyo + 0.5f * cnoise[3 * ai + 1];
        out[3 * ai + 2] = czo + 0.5f * cnoise[3 * ai + 2];
    }
}

extern "C" void kernel_launch(void* const* d_in, const int* in_sizes, int n_in,
                              void* d_out, int out_size, void* d_ws, size_t ws_size,
                              hipStream_t stream) {
    const float* X          = (const float*)d_in[0];
    const float* base_noise = (const float*)d_in[1];
    const float* cnoise     = (const float*)d_in[2];
    const int*   block_ids  = (const int*)d_in[3];
    const unsigned int* gmask = (const unsigned int*)d_in[4];
    float* out = (float*)d_out;

    char* ws = (char*)d_ws;
    int*    counts     = (int*)(ws + OFF_COUNTS);
    int*    blk_gen    = (int*)(ws + OFF_BLKGEN);
    int*    blk_goff   = (int*)(ws + OFF_BLKGOFF);
    unsigned long long* flags = (unsigned long long*)(ws + OFF_FLAGS);
    int*    cell_cnt   = (int*)(ws + OFF_CNT);
    int*    cell_start = (int*)(ws + OFF_START);
    int*    genidx     = (int*)(ws + OFF_GENIDX);
    float4* ctx4s      = (float4*)(ws + OFF_CTX4);

    k0_zero<<<NCELLS_PAD / 1024, 256, 0, stream>>>((int4*)cell_cnt);
    k1_classify<<<NBLK, NTHR, 0, stream>>>(X, block_ids, gmask, base_noise,
                                           out, flags, blk_gen, cell_cnt);
    k2_scan<<<1, 1024, 0, stream>>>(cell_cnt, cell_start, blk_gen, blk_goff, counts);
    k3_scatter<<<NBLK, NTHR, 0, stream>>>(X, flags, blk_goff, cell_start,
                                          cell_cnt, ctx4s, genidx);
    // BISECTION PROBE: k4 is idempotent (same deterministic writes).
    // Launch 3x: if total stays ~51us, k4 is ~5us and the ~50us plateau is a
    // harness-level concurrent floor (poison fill). If total jumps ~+2x k4,
    // k4 is the real cost and the floor theory is dead.
    k4_search<<<N_ATOMS / 8, 512, 0, stream>>>(X, cnoise, counts, cell_start,
                                               ctx4s, genidx, out);
    k4_search<<<N_ATOMS / 8, 512, 0, stream>>>(X, cnoise, counts, cell_start,
                                               ctx4s, genidx, out);
    k4_search<<<N_ATOMS / 8, 512, 0, stream>>>(X, cnoise, counts, cell_start,
                                               ctx4s, genidx, out);
}

// Round 15
// 46.007 us; speedup vs baseline: 2.2635x; 2.2635x over previous
//
#include <hip/hip_runtime.h>
#include <cstdint>

#define N_ATOMS 16384
#define NBLK 64
#define NTHR 256
#define G 24
#define NCELLS 13824
#define NCELLS_PAD 14336
#define CPT 14                    // cells per thread in k2 (1024 thr)
#define BOX_LO -48.0f
#define INV_CELL 0.25f            // cell side 4.0
#define SINIT 3.0e38f

// ws layout (~476 KB < 590 KB proven):
#define OFF_COUNTS 0              // int[2]: n_ctx, n_gen
#define OFF_BLKGEN 256            // int[64]
#define OFF_BLKGOFF 512           // int[64]
#define OFF_FLAGS 1024            // u64[256] gen bit per atom
#define OFF_ACELL 3072            // u16[16384] per-atom cell (0xFFFF = gen)
#define OFF_POS 35840             // int[16384] ctx scatter position
#define OFF_START 101376          // int[14337] cell starts
#define OFF_GENIDX 158976         // int[16384]
#define OFF_CTX4 224512           // float4[16384] cell-sorted (x,y,z,|x|^2)

__device__ __forceinline__ int cell1(float x) {
    int c = (int)floorf((x - BOX_LO) * INV_CELL);
    return min(max(c, 0), G - 1);
}

__device__ __forceinline__ void ins3(float v, int vi,
                                     float& s1, float& s2, float& s3,
                                     int& i1, int& i2, int& i3)
{
    const bool b1 = v < s1, b2 = v < s2, b3 = v < s3;
    s3 = b2 ? s2 : (b3 ? v : s3);   i3 = b2 ? i2 : (b3 ? vi : i3);
    s2 = b1 ? s1 : (b2 ? v : s2);   i2 = b1 ? i1 : (b2 ? vi : i2);
    s1 = b1 ? v : s1;               i1 = b1 ? vi : i1;
}

// K1: classify + base_noise + gen flags + per-atom cell id (no atomics)
__global__ __launch_bounds__(NTHR)
void k1_classify(const float* __restrict__ X,
                 const int* __restrict__ block_ids,
                 const unsigned int* __restrict__ mask,
                 const float* __restrict__ base_noise,
                 float* __restrict__ out,
                 unsigned long long* __restrict__ flags,
                 int* __restrict__ blk_gen,
                 unsigned short* __restrict__ acell)
{
    __shared__ int sflag;
    __shared__ int wg[4];
    const int t = threadIdx.x;
    const int wave = t >> 6, lane = t & 63;

    // mask dtype probe: int32 0/1 values vs packed bool bytes (R2-R14 validated)
    if (t == 0) sflag = 0;
    __syncthreads();
    if (mask[t] > 1u) sflag = 1;    // benign same-value race
    __syncthreads();
    const bool is_u8 = (sflag != 0);
    const unsigned char* m8 = (const unsigned char*)mask;

    const int i = blockIdx.x * NTHR + t;
    const int bid = block_ids[i];
    const bool g = is_u8 ? (m8[bid] != 0) : (mask[bid] != 0u);

    out[3 * i + 0] = base_noise[3 * i + 0];
    out[3 * i + 1] = base_noise[3 * i + 1];
    out[3 * i + 2] = base_noise[3 * i + 2];

    const unsigned long long mg = __ballot(g);
    if (lane == 0) { flags[blockIdx.x * 4 + wave] = mg; wg[wave] = __popcll(mg); }
    __syncthreads();
    if (t == 0) blk_gen[blockIdx.x] = wg[0] + wg[1] + wg[2] + wg[3];

    unsigned short c = 0xFFFFu;
    if (!g) {
        const float x = X[3 * i], y = X[3 * i + 1], z = X[3 * i + 2];
        c = (unsigned short)((cell1(z) * G + cell1(y)) * G + cell1(x));
    }
    acell[i] = c;
}

// K2: single-block LDS counting sort: histogram -> scan -> positions.
// Also gen-block prefix + counts.
__global__ __launch_bounds__(1024)
void k2_sort(const unsigned short* __restrict__ acell,
             int* __restrict__ cell_start,
             int* __restrict__ pos,
             const int* __restrict__ blk_gen,
             int* __restrict__ blk_goff,
             int* __restrict__ counts)
{
    __shared__ int hist[NCELLS_PAD];          // 57,344 B
    __shared__ int wsum[16], wexc[16];
    const int t = threadIdx.x;
    const int wave = t >> 6, lane = t & 63;

    #pragma unroll
    for (int k = 0; k < CPT; ++k) hist[t * CPT + k] = 0;
    __syncthreads();

    // pass 1: histogram (LDS atomics, coalesced u16 reads)
    #pragma unroll
    for (int it = 0; it < N_ATOMS / 1024; ++it) {
        const unsigned short c = acell[it * 1024 + t];
        if (c != 0xFFFFu) atomicAdd(&hist[c], 1);
    }
    __syncthreads();

    // scan: 14 cells/thread, wave prefix, cross-wave prefix
    int loc[CPT]; int sum = 0;
    #pragma unroll
    for (int k = 0; k < CPT; ++k) {
        const int v = hist[t * CPT + k];
        loc[k] = sum; sum += v;
    }
    int v = sum;
    #pragma unroll
    for (int d = 1; d < 64; d <<= 1) { const int u = __shfl_up(v, d); if (lane >= d) v += u; }
    if (lane == 63) wsum[wave] = v;
    __syncthreads();
    if (t < 16) {
        int v2 = wsum[t];
        const int orig = v2;
        #pragma unroll
        for (int d = 1; d < 16; d <<= 1) { const int u = __shfl_up(v2, d); if (t >= d) v2 += u; }
        wexc[t] = v2 - orig;
    }
    __syncthreads();
    const int base = wexc[wave] + (v - sum);
    #pragma unroll
    for (int k = 0; k < CPT; ++k) {
        const int st = base + loc[k];
        cell_start[t * CPT + k] = st;
        hist[t * CPT + k] = st;               // -> cursor
    }
    if (t == 1023) cell_start[NCELLS_PAD] = base + sum;   // = n_ctx
    __syncthreads();

    // pass 2: absolute scatter positions (cursor atomicAdd returns start+rank)
    #pragma unroll
    for (int it = 0; it < N_ATOMS / 1024; ++it) {
        const int i = it * 1024 + t;
        const unsigned short c = acell[i];
        if (c != 0xFFFFu) pos[i] = atomicAdd(&hist[c], 1);
    }

    // gen-block prefix + counts
    if (t < 64) {
        const int o = blk_gen[t];
        int s = o;
        #pragma unroll
        for (int d = 1; d < 64; d <<= 1) { const int u = __shfl_up(s, d); if (t >= d) s += u; }
        blk_goff[t] = s - o;
        if (t == 63) { counts[1] = s; counts[0] = N_ATOMS - s; }
    }
}

// K3: scatter (no atomics)
__global__ __launch_bounds__(NTHR)
void k3_scatter(const float* __restrict__ X,
                const unsigned long long* __restrict__ flags,
                const int* __restrict__ blk_goff,
                const int* __restrict__ pos,
                float4* __restrict__ ctx4s,
                int* __restrict__ genidx)
{
    const int t = threadIdx.x;
    const int wave = t >> 6, lane = t & 63;
    const int i = blockIdx.x * NTHR + t;
    const unsigned long long fw = flags[blockIdx.x * 4 + wave];
    const bool g = (fw >> lane) & 1ull;
    if (g) {
        int og = blk_goff[blockIdx.x];
        #pragma unroll
        for (int w = 0; w < 4; ++w) {
            if (w < wave) og += __popcll(flags[blockIdx.x * 4 + w]);
        }
        const unsigned long long below = (1ull << lane) - 1ull;
        og += __popcll(fw & below);
        genidx[og] = i;
    } else {
        const float x = X[3 * i], y = X[3 * i + 1], z = X[3 * i + 2];
        float xn = x * x; xn += y * y; xn += z * z;
        ctx4s[pos[i]] = make_float4(x, y, z, xn);
    }
}

// K4: one wave per gen atom; shuffle-free r<=1 common path (R13) + compact
// segment-enumerated ring levels (P,R] = (1,2],(2,4],(4,8]; ballot
// convergence; exhaustive restart fallback; single final index merge.
__global__ __launch_bounds__(NTHR)
void k4_search(const float* __restrict__ X,
               const float* __restrict__ cnoise,
               const int* __restrict__ counts,
               const int* __restrict__ cell_start,
               const float4* __restrict__ ctx4s,
               const int* __restrict__ genidx,
               float* __restrict__ out)
{
    const int n_gen = counts[1];
    const int wave = threadIdx.x >> 6, lane = threadIdx.x & 63;
    if ((int)blockIdx.x * 4 >= n_gen) return;
    const int slot = (int)blockIdx.x * 4 + wave;
    if (slot >= n_gen) return;

    const int ai = genidx[slot];
    const float qx = X[3 * ai], qy = X[3 * ai + 1], qz = X[3 * ai + 2];
    float xnq = qx * qx; xnq += qy * qy; xnq += qz * qz;
    const int cqx = cell1(qx), cqy = cell1(qy), cqz = cell1(qz);

    float s1 = SINIT, s2 = SINIT, s3 = SINIT;
    int i1 = 0, i2 = 0, i3 = 0;

    // ---- phase A: r<=1 box as 9 row-segments, shuffle-free scan ----
    {
        int st = 0, cnt = 0;
        if (lane < 9) {
            const int dy = lane % 3 - 1, dz = lane / 3 - 1;
            const int cy = cqy + dy, cz = cqz + dz;
            if ((unsigned)cy < G && (unsigned)cz < G) {
                const int xlo = max(cqx - 1, 0), xhi = min(cqx + 1, G - 1);
                const int c0 = (cz * G + cy) * G + xlo;
                st = cell_start[c0];
                cnt = cell_start[c0 + (xhi - xlo + 1)] - st;
            }
        }
        int stv[9], base[10];
        base[0] = 0;
        #pragma unroll
        for (int k = 0; k < 9; ++k) {
            stv[k] = __builtin_amdgcn_readlane(st, k);     // VALU, uniform
            base[k + 1] = base[k] + __builtin_amdgcn_readlane(cnt, k);
        }
        const int T = base[9];
        const int nro = (T + 63) >> 6;
        if (nro > 0) {
            auto calcP = [&](int j) -> int {
                const int jc = min(j, T - 1);
                int p = stv[0] + jc;
                #pragma unroll
                for (int k = 1; k < 9; ++k)
                    p = (jc >= base[k]) ? stv[k] + (jc - base[k]) : p;
                return p;
            };
            int p0 = calcP(lane);
            float4 cc0 = ctx4s[p0];
            for (int ro = 0; ro < nro; ++ro) {
                int p1 = p0; float4 cc1 = cc0;
                if (ro + 1 < nro) { p1 = calcP((ro + 1) * 64 + lane); cc1 = ctx4s[p1]; }
                if (ro * 64 + lane < T) {
                    const float dot = qx * cc0.x + qy * cc0.y + qz * cc0.z;
                    const float sq = (xnq + cc0.w) - 2.0f * dot;
                    ins3(sq, p0, s1, s2, s3, i1, i2, i3);
                }
                p0 = p1; cc0 = cc1;
            }
        }
    }

    // ballot-count convergence: >=3 values with v+0.01<bnd  <=>  m3+0.01<bnd
    auto converged = [&](float bnd) -> bool {
        const int c = __popcll(__ballot(s1 + 0.01f < bnd))
                    + __popcll(__ballot(s2 + 0.01f < bnd))
                    + __popcll(__ballot(s3 + 0.01f < bnd));
        return c >= 3;
    };

    bool done = converged(16.0f);            // bnd = (4*1)^2

    if (!done) {
        auto searchOwner = [&](int ebase_r, int jc) -> int {
            int L = 0;
            #pragma unroll
            for (int stp = 32; stp >= 1; stp >>= 1) {
                const int cand = L + stp;
                const int bv = __shfl(ebase_r, cand);
                if (bv <= jc) L = cand;
            }
            return L;
        };
        auto flatScan = [&](int T, int ebase_r, int pk_r) {
            const int iters = (T + 63) >> 6;
            if (iters == 0) return;
            int jc0 = min(lane, T - 1);
            int p0 = __shfl(pk_r, searchOwner(ebase_r, jc0)) + jc0;
            float4 cc0 = ctx4s[p0];
            for (int it = 0; it < iters; ++it) {
                int p1 = p0; float4 cc1 = cc0;
                if (it + 1 < iters) {
                    const int jc1 = min((it + 1) * 64 + lane, T - 1);
                    p1 = __shfl(pk_r, searchOwner(ebase_r, jc1)) + jc1;
                    cc1 = ctx4s[p1];
                }
                if (it * 64 + lane < T) {
                    const float dot = qx * cc0.x + qy * cc0.y + qz * cc0.z;
                    const float sq = (xnq + cc0.w) - 2.0f * dot;
                    ins3(sq, p0, s1, s2, s3, i1, i2, i3);
                }
                p0 = p1; cc0 = cc1;
            }
        };
        auto prefixT = [&](int cnt, int& ebase_r, int& T) {
            int pre = cnt;
            #pragma unroll
            for (int d = 1; d < 64; d <<= 1) {
                const int u = __shfl_up(pre, d);
                if (lane >= d) pre += u;
            }
            T = __shfl(pre, 63);
            ebase_r = pre - cnt;
        };
        // ring (P,R] via exact segment list: A full rows (|dz|>P), C full rows
        // (|dz|<=P,|dy|>P), D = 2*(2P+1)^2 inner flank segments. Disjoint,
        // covers ring exactly; levels disjoint from phase A and each other.
        auto ringScan = [&](int P, int R) {
            const int B = 2 * R + 1;
            const int RP = R - P;
            const int PP = 2 * P + 1;
            const int A = 2 * RP * B;
            const int C = PP * 2 * RP;
            const int NS = A + C + 2 * PP * PP;
            auto segRange = [&](int u, int& st, int& cnt) {
                st = 0; cnt = 0;
                if (u >= NS) return;
                int dy, dz, xlo, xhi;
                if (u < A) {
                    const int q = u / B, rdy = u - q * B;
                    dz = (q < RP) ? (-R + q) : (P + 1 + (q - RP));
                    dy = rdy - R;
                    xlo = cqx - R; xhi = cqx + R;
                } else if (u < A + C) {
                    const int v = u - A, W = 2 * RP;
                    const int q = v / W, w = v - q * W;
                    dz = -P + q;
                    dy = (w < RP) ? (-R + w) : (P + 1 + (w - RP));
                    xlo = cqx - R; xhi = cqx + R;
                } else {
                    const int v = u - A - C;
                    const int side = v & 1, v2 = v >> 1;
                    dy = v2 % PP - P; dz = v2 / PP - P;
                    if (side) { xlo = cqx + P + 1; xhi = cqx + R; }
                    else      { xlo = cqx - R;     xhi = cqx - P - 1; }
                }
                const int cy = cqy + dy, cz = cqz + dz;
                if ((unsigned)cy >= G || (unsigned)cz >= G) return;
                xlo = max(xlo, 0); xhi = min(xhi, G - 1);
                if (xlo > xhi) return;
                const int c0 = (cz * G + cy) * G + xlo;
                st = cell_start[c0];
                cnt = cell_start[c0 + (xhi - xlo + 1)] - st;
            };
            const int nro = (NS + 63) >> 6;
            int st0, c0r;
            segRange(lane, st0, c0r);
            for (int ro = 0; ro < nro; ++ro) {
                int st1 = st0, c1r = c0r;
                if (ro + 1 < nro) segRange((ro + 1) * 64 + lane, st1, c1r);
                int eb, Tr;
                prefixT(c0r, eb, Tr);
                if (Tr > 0) flatScan(Tr, eb, st0 - eb);
                st0 = st1; c0r = c1r;
            }
        };

        #pragma unroll
        for (int li = 1; li < 4; ++li) {
            if (!done) {
                const int R = 1 << li;                 // 2,4,8
                ringScan(1 << (li - 1), R);
                done = converged((float)(4 * R) * (float)(4 * R));
            }
        }
        if (!done) {
            // exhaustive restart (exact, duplicate-free; ~never taken)
            s1 = SINIT; s2 = SINIT; s3 = SINIT;
            i1 = 0; i2 = 0; i3 = 0;
            const int n_ctx = counts[0];
            for (int base = 0; base < n_ctx; base += 64) {
                const int p = base + lane;
                if (p < n_ctx) {
                    const float4 cc = ctx4s[p];
                    const float dot = qx * cc.x + qy * cc.y + qz * cc.z;
                    const float sq = (xnq + cc.w) - 2.0f * dot;
                    ins3(sq, p, s1, s2, s3, i1, i2, i3);
                }
            }
        }
    }

    // final full merge with indices (each candidate lives in exactly one lane)
    #pragma unroll
    for (int m = 1; m < 64; m <<= 1) {
        const float a = __shfl_xor(s1, m); const int ja = __shfl_xor(i1, m);
        const float b = __shfl_xor(s2, m); const int jb = __shfl_xor(i2, m);
        const float c = __shfl_xor(s3, m); const int jc = __shfl_xor(i3, m);
        ins3(a, ja, s1, s2, s3, i1, i2, i3);
        ins3(b, jb, s1, s2, s3, i1, i2, i3);
        ins3(c, jc, s1, s2, s3, i1, i2, i3);
    }

    if (lane == 0) {
        const float d1 = sqrtf(fmaxf(s1, 0.0f) + 1e-12f);
        const float d2 = sqrtf(fmaxf(s2, 0.0f) + 1e-12f);
        const float d3 = sqrtf(fmaxf(s3, 0.0f) + 1e-12f);
        float w1 = 1.0f / (d1 + 1e-8f);
        float w2 = 1.0f / (d2 + 1e-8f);
        float w3 = 1.0f / (d3 + 1e-8f);
        float wsum = w1 + w2;
        wsum += w3;
        w1 /= wsum; w2 /= wsum; w3 /= wsum;
        const float4 c1 = ctx4s[i1];
        const float4 c2 = ctx4s[i2];
        const float4 c3 = ctx4s[i3];
        float cxo = w1 * c1.x + w2 * c2.x; cxo += w3 * c3.x;
        float cyo = w1 * c1.y + w2 * c2.y; cyo += w3 * c3.y;
        float czo = w1 * c1.z + w2 * c2.z; czo += w3 * c3.z;
        out[3 * ai + 0] = cxo + 0.5f * cnoise[3 * ai + 0];
        out[3 * ai + 1] = cyo + 0.5f * cnoise[3 * ai + 1];
        out[3 * ai + 2] = czo + 0.5f * cnoise[3 * ai + 2];
    }
}

extern "C" void kernel_launch(void* const* d_in, const int* in_sizes, int n_in,
                              void* d_out, int out_size, void* d_ws, size_t ws_size,
                              hipStream_t stream) {
    const float* X          = (const float*)d_in[0];
    const float* base_noise = (const float*)d_in[1];
    const float* cnoise     = (const float*)d_in[2];
    const int*   block_ids  = (const int*)d_in[3];
    const unsigned int* gmask = (const unsigned int*)d_in[4];
    float* out = (float*)d_out;

    char* ws = (char*)d_ws;
    int*    counts     = (int*)(ws + OFF_COUNTS);
    int*    blk_gen    = (int*)(ws + OFF_BLKGEN);
    int*    blk_goff   = (int*)(ws + OFF_BLKGOFF);
    unsigned long long* flags = (unsigned long long*)(ws + OFF_FLAGS);
    unsigned short* acell = (unsigned short*)(ws + OFF_ACELL);
    int*    pos        = (int*)(ws + OFF_POS);
    int*    cell_start = (int*)(ws + OFF_START);
    int*    genidx     = (int*)(ws + OFF_GENIDX);
    float4* ctx4s      = (float4*)(ws + OFF_CTX4);

    k1_classify<<<NBLK, NTHR, 0, stream>>>(X, block_ids, gmask, base_noise,
                                           out, flags, blk_gen, acell);
    k2_sort<<<1, 1024, 0, stream>>>(acell, cell_start, pos, blk_gen, blk_goff, counts);
    k3_scatter<<<NBLK, NTHR, 0, stream>>>(X, flags, blk_goff, pos, ctx4s, genidx);
    k4_search<<<N_ATOMS / 4, NTHR, 0, stream>>>(X, cnoise, counts, cell_start,
                                                ctx4s, genidx, out);
}